// Round 1
// baseline (697.642 us; speedup 1.0000x reference)
//
#include <hip/hip_runtime.h>

#define GLOBAL_AS __attribute__((address_space(1)))
#define LDS_AS    __attribute__((address_space(3)))

typedef __bf16 bf16_t;
typedef __bf16 bf16x8 __attribute__((ext_vector_type(8)));
typedef __bf16 bf16x4 __attribute__((ext_vector_type(4)));
typedef float  f32x4  __attribute__((ext_vector_type(4)));

// Problem constants (B=64, S=1024, D=768)
#define BATCH 64
#define SEQ   1024
#define DIM   768
#define BS_ROWS (BATCH * SEQ)            // 65536

__device__ __forceinline__ void gl2lds16(const void* g, void* l) {
    __builtin_amdgcn_global_load_lds((GLOBAL_AS const void*)g, (LDS_AS void*)l, 16, 0, 0);
}

// ---------------- fp32 -> bf16 convert (8 elems/thread) ----------------
__global__ void k_convert(const float* __restrict__ x, bf16_t* __restrict__ y, int n8) {
    int gid = blockIdx.x * 256 + threadIdx.x;
    if (gid >= n8) return;
    const float4* xp = (const float4*)x;
    float4 a = xp[gid * 2];
    float4 b = xp[gid * 2 + 1];
    bf16x8 v;
    v[0] = (bf16_t)a.x; v[1] = (bf16_t)a.y; v[2] = (bf16_t)a.z; v[3] = (bf16_t)a.w;
    v[4] = (bf16_t)b.x; v[5] = (bf16_t)b.y; v[6] = (bf16_t)b.z; v[7] = (bf16_t)b.w;
    ((bf16x8*)y)[gid] = v;
}

// ---------------- Asym = A + A^T, cast bf16 ----------------
__global__ void k_asym(const float* __restrict__ A, bf16_t* __restrict__ S_, int n) {
    int idx = blockIdx.x * 256 + threadIdx.x;
    if (idx >= n) return;
    int d = idx / DIM;
    int e = idx - d * DIM;
    S_[idx] = (bf16_t)(A[idx] + A[e * DIM + d]);
}

// ---------------- GEMM core macro pieces (m97 structure) ----------------
// C[i][j] = sum_k Arow[i][k] * Brow[j][k]   (both K-contiguous, ld = DIM)
// Block: 256 thr = 4 waves (2x2 of 64x64), tile 128x128, BK=32.
// LDS linear in staging-lane order (global_load_lds constraint); the global
// 16B segment each lane fetches is XOR-swizzled so ds_read_b128 fragment
// reads are bank-conflict-free.

// ---------------- GEMM1: M = H @ Asym (Asym symmetric => B=Asym rows) ----
__global__ void k_gemm1(const bf16_t* __restrict__ H, const bf16_t* __restrict__ Ag,
                        bf16_t* __restrict__ M) {
    __shared__ bf16_t Asm[128 * 32];
    __shared__ bf16_t Bsm[128 * 32];
    const int t = threadIdx.x;
    const int row0 = blockIdx.y * 128;
    const int col0 = blockIdx.x * 128;
    const int ln = t & 63, w = t >> 6;
    const int wr = w >> 1, wc = w & 1;
    const int r = ln & 15, qd = ln >> 4;
    const int sseg = qd ^ ((r >> 1) & 3);      // swizzled read segment

    // staging: thread t -> LDS elem t*8 (issue h adds h*2048); row h*64+(t>>2)
    const int srow = t >> 2;
    const int gseg = (t & 3) ^ ((t >> 3) & 3); // swizzled global segment
    const bf16_t* gA0 = H  + (size_t)(row0 + srow) * DIM + gseg * 8;
    const bf16_t* gA1 = gA0 + (size_t)64 * DIM;
    const bf16_t* gB0 = Ag + (size_t)(col0 + srow) * DIM + gseg * 8;
    const bf16_t* gB1 = gB0 + (size_t)64 * DIM;

    f32x4 acc[4][4] = {};

    for (int k0 = 0; k0 < DIM; k0 += 32) {
        gl2lds16(gA0 + k0, &Asm[t * 8]);
        gl2lds16(gA1 + k0, &Asm[2048 + t * 8]);
        gl2lds16(gB0 + k0, &Bsm[t * 8]);
        gl2lds16(gB1 + k0, &Bsm[2048 + t * 8]);
        __syncthreads();   // drains vmcnt (global_load_lds) before reads

        bf16x8 af[4], bf[4];
#pragma unroll
        for (int mt = 0; mt < 4; ++mt) {
            int m = wr * 64 + mt * 16 + r;
            af[mt] = *(const bf16x8*)&Asm[m * 32 + sseg * 8];
        }
#pragma unroll
        for (int nt = 0; nt < 4; ++nt) {
            int n = wc * 64 + nt * 16 + r;
            bf[nt] = *(const bf16x8*)&Bsm[n * 32 + sseg * 8];
        }
#pragma unroll
        for (int mt = 0; mt < 4; ++mt)
#pragma unroll
            for (int nt = 0; nt < 4; ++nt)
                acc[mt][nt] = __builtin_amdgcn_mfma_f32_16x16x32_bf16(
                    af[mt], bf[nt], acc[mt][nt], 0, 0, 0);
        __syncthreads();
    }

    // epilogue: C/D layout col=lane&15, row=(lane>>4)*4+reg
#pragma unroll
    for (int mt = 0; mt < 4; ++mt) {
#pragma unroll
        for (int rI = 0; rI < 4; ++rI) {
            int row = row0 + wr * 64 + mt * 16 + qd * 4 + rI;
            size_t base = (size_t)row * DIM + col0 + wc * 64;
#pragma unroll
            for (int nt = 0; nt < 4; ++nt)
                M[base + nt * 16 + r] = (bf16_t)acc[mt][nt][rI];
        }
    }
}

// ---------------- q[row] = 0.5 * dot(M[row], H[row]) ----------------
__global__ void k_q(const bf16_t* __restrict__ M, const bf16_t* __restrict__ H,
                    float* __restrict__ qv) {
    int t = threadIdx.x;
    int w = t >> 6, ln = t & 63;
    int row = blockIdx.x * 4 + w;
    const bf16_t* mp = M + (size_t)row * DIM;
    const bf16_t* hp = H + (size_t)row * DIM;
    float acc = 0.f;
#pragma unroll
    for (int j = 0; j < 3; ++j) {
        int e = j * 256 + ln * 4;
        bf16x4 mv = *(const bf16x4*)&mp[e];
        bf16x4 hv = *(const bf16x4*)&hp[e];
#pragma unroll
        for (int u = 0; u < 4; ++u) acc += (float)mv[u] * (float)hv[u];
    }
#pragma unroll
    for (int off = 32; off > 0; off >>= 1) acc += __shfl_down(acc, off, 64);
    if (ln == 0) qv[row] = 0.5f * acc;
}

// ---------------- GEMM2 per batch: G = M_b @ H_b^T, dists = q_i+q_j-G ----
__global__ void k_gemm2(const bf16_t* __restrict__ M, const bf16_t* __restrict__ H,
                        const float* __restrict__ qv, float* __restrict__ out) {
    __shared__ bf16_t Asm[128 * 32];
    __shared__ bf16_t Bsm[128 * 32];
    const int t = threadIdx.x;
    const int b = blockIdx.z;
    const int row0 = blockIdx.y * 128;
    const int col0 = blockIdx.x * 128;
    const int ln = t & 63, w = t >> 6;
    const int wr = w >> 1, wc = w & 1;
    const int r = ln & 15, qd = ln >> 4;
    const int sseg = qd ^ ((r >> 1) & 3);

    const bf16_t* Mb = M + (size_t)b * SEQ * DIM;
    const bf16_t* Hb = H + (size_t)b * SEQ * DIM;

    const int srow = t >> 2;
    const int gseg = (t & 3) ^ ((t >> 3) & 3);
    const bf16_t* gA0 = Mb + (size_t)(row0 + srow) * DIM + gseg * 8;
    const bf16_t* gA1 = gA0 + (size_t)64 * DIM;
    const bf16_t* gB0 = Hb + (size_t)(col0 + srow) * DIM + gseg * 8;
    const bf16_t* gB1 = gB0 + (size_t)64 * DIM;

    f32x4 acc[4][4] = {};

    for (int k0 = 0; k0 < DIM; k0 += 32) {
        gl2lds16(gA0 + k0, &Asm[t * 8]);
        gl2lds16(gA1 + k0, &Asm[2048 + t * 8]);
        gl2lds16(gB0 + k0, &Bsm[t * 8]);
        gl2lds16(gB1 + k0, &Bsm[2048 + t * 8]);
        __syncthreads();

        bf16x8 af[4], bf[4];
#pragma unroll
        for (int mt = 0; mt < 4; ++mt) {
            int m = wr * 64 + mt * 16 + r;
            af[mt] = *(const bf16x8*)&Asm[m * 32 + sseg * 8];
        }
#pragma unroll
        for (int nt = 0; nt < 4; ++nt) {
            int n = wc * 64 + nt * 16 + r;
            bf[nt] = *(const bf16x8*)&Bsm[n * 32 + sseg * 8];
        }
#pragma unroll
        for (int mt = 0; mt < 4; ++mt)
#pragma unroll
            for (int nt = 0; nt < 4; ++nt)
                acc[mt][nt] = __builtin_amdgcn_mfma_f32_16x16x32_bf16(
                    af[mt], bf[nt], acc[mt][nt], 0, 0, 0);
        __syncthreads();
    }

    const float* qb = qv + b * SEQ;
    float qc[4];
#pragma unroll
    for (int nt = 0; nt < 4; ++nt) qc[nt] = qb[col0 + wc * 64 + nt * 16 + r];

#pragma unroll
    for (int mt = 0; mt < 4; ++mt) {
#pragma unroll
        for (int rI = 0; rI < 4; ++rI) {
            int row = row0 + wr * 64 + mt * 16 + qd * 4 + rI;
            float qr = qb[row];
            size_t base = ((size_t)b * SEQ + row) * SEQ + col0 + wc * 64;
#pragma unroll
            for (int nt = 0; nt < 4; ++nt)
                out[base + nt * 16 + r] = qr + qc[nt] - acc[mt][nt][rI];
        }
    }
}

extern "C" void kernel_launch(void* const* d_in, const int* in_sizes, int n_in,
                              void* d_out, int out_size, void* d_ws, size_t ws_size,
                              hipStream_t stream) {
    const float* batch = (const float*)d_in[0];  // (64,1024,768) fp32
    const float* proj  = (const float*)d_in[1];  // (768,768) fp32
    float* out = (float*)d_out;                  // (64,1024,1024) fp32

    char* ws = (char*)d_ws;
    // Workspace layout (all 16B-aligned):
    //   Hb:  BS_ROWS*DIM bf16  = 100663296 B  @ 0
    //   Mb:  BS_ROWS*DIM bf16  = 100663296 B  @ 100663296
    //   Ab:  DIM*DIM bf16      =   1179648 B  @ 201326592
    //   qv:  BS_ROWS fp32      =    262144 B  @ 202506240
    bf16_t* Hb = (bf16_t*)ws;
    bf16_t* Mb = (bf16_t*)(ws + 100663296);
    bf16_t* Ab = (bf16_t*)(ws + 201326592);
    float*  qv = (float*)(ws + 202506240);

    // 1) batch -> bf16 (50331648 elems / 8 per thread)
    k_convert<<<24576, 256, 0, stream>>>(batch, Hb, 6291456);
    // 2) Asym = A + A^T in bf16
    k_asym<<<2304, 256, 0, stream>>>(proj, Ab, DIM * DIM);
    // 3) M = H @ Asym   (65536 x 768, K=768)
    k_gemm1<<<dim3(DIM / 128, BS_ROWS / 128), 256, 0, stream>>>(Hb, Ab, Mb);
    // 4) q = 0.5 * rowdot(M, H)
    k_q<<<BS_ROWS / 4, 256, 0, stream>>>(Mb, Hb, qv);
    // 5) per-batch G = M H^T with fused epilogue dists = q_i + q_j - G_ij
    k_gemm2<<<dim3(SEQ / 128, SEQ / 128, BATCH), 256, 0, stream>>>(Mb, Hb, qv, out);
}